// Round 6
// baseline (154.341 us; speedup 1.0000x reference)
//
#include <hip/hip_runtime.h>
#include <hip/hip_bf16.h>

// Linear layer: out[M,N] = x[M,K] @ W[N,K]^T + b[N], fp32 in/out.
// M=32768, N=512, K=512.
// R6: A-tile staged fp32 via global_load_lds (no VGPR roundtrip; deep
// in-flight DMA) with XOR chunk swizzle (global-side inverse) to kill the
// 128B-row 16-way bank conflict; W-tile via register staging -> bf16 LDS
// (W is L2-resident, low latency). Frags: A read fp32+cvt, W read bf16.
// 2-barrier m97-style K-loop; DMA(kt+1) issued after barrier2.

#define M_DIM 32768
#define N_DIM 512
#define K_DIM 512
#define BK 32
#define LDW 36   // W LDS row stride (bf16): 72B rows -> 2-way banks via b64 reads

typedef __bf16 bf16x8 __attribute__((ext_vector_type(8)));
typedef __bf16 bf16x4 __attribute__((ext_vector_type(4)));
typedef float floatx4 __attribute__((ext_vector_type(4)));

__global__ __launch_bounds__(256) void linear_dma(
    const float* __restrict__ A,    // [M, K]
    const float* __restrict__ W,    // [N, K]
    const float* __restrict__ bias, // [N]
    float* __restrict__ C)          // [M, N]
{
    // sA: 128 rows x 8 chunks(16B) fp32, XOR-swizzled: chunk (r,p) holds
    // global col-chunk p^(r&7). 16KB, rows 128B-aligned.
    __shared__ float sA[128 * 32];
    __shared__ __bf16 sW[128 * LDW];  // 9216B

    const int t = threadIdx.x;
    const int bid = blockIdx.x;
    // XCD swizzle (R2-proven: FETCH 133->39MB).
    const int nT = (bid >> 3) & 3;
    const int mT = (bid & 7) | ((bid >> 5) << 3);
    const int mBlock = mT * 128;
    const int nBlock = nT * 128;

    const int wave = t >> 6;
    const int lane = t & 63;
    const int mW = (wave >> 1) * 64;
    const int nW = (wave & 1) * 64;
    const int kh = lane >> 4;
    const int l16 = lane & 15;
    // DMA inverse swizzle: lane l covers row-in-group l>>3, LDS chunk pos l&7,
    // which must hold global col-chunk (l&7)^(row&7) = (l&7)^(l>>3).
    const int swz = (lane & 7) ^ (lane >> 3);

    // A-DMA: wave v stages rows [v*32, v*32+32) as 4 instrs of 8 rows.
    const float* aDma[4];
#pragma unroll
    for (int j = 0; j < 4; ++j)
        aDma[j] = A + (size_t)(mBlock + wave * 32 + j * 8 + (lane >> 3)) * K_DIM
                    + swz * 4;

    // W register staging (R1 path): thread t covers rows sRow+{0,32,64,96},
    // 4 floats at col sCol; coalesced.
    const int sRow = t >> 3;
    const int sCol = (t & 7) * 4;
    const float* wBase = W + (size_t)(nBlock + sRow) * K_DIM + sCol;

    floatx4 acc[4][4];
#pragma unroll
    for (int i = 0; i < 4; ++i)
#pragma unroll
        for (int j = 0; j < 4; ++j)
            acc[i][j] = (floatx4)0.f;

    // Prologue: DMA A-tile(0), load W regs(0).
#pragma unroll
    for (int j = 0; j < 4; ++j)
        __builtin_amdgcn_global_load_lds(
            (const __attribute__((address_space(1))) void*)(aDma[j]),
            (__attribute__((address_space(3))) void*)&sA[(wave * 32 + j * 8) * 32],
            16, 0, 0);
    floatx4 pw[4];
#pragma unroll
    for (int i = 0; i < 4; ++i)
        pw[i] = *(const floatx4*)(wBase + (size_t)i * 32 * K_DIM);

    for (int kt = 0; kt < K_DIM; kt += BK) {
        // W: cvt + store to LDS (pw already drained by prior barrier/prologue).
#pragma unroll
        for (int i = 0; i < 4; ++i) {
            bf16x4 wb;
#pragma unroll
            for (int j = 0; j < 4; ++j) wb[j] = (__bf16)pw[i][j];
            *(bf16x4*)&sW[(sRow + i * 32) * LDW + sCol] = wb;
        }
        __syncthreads();  // drains A-DMA(kt) + makes W writes visible

        // A frags: swizzled fp32 chunks -> cvt bf16.
        bf16x8 aF[4], wF[4];
#pragma unroll
        for (int i = 0; i < 4; ++i) {
            const int r = mW + i * 16 + l16;
            const int p0 = (2 * kh) ^ (r & 7);
            floatx4 c0 = *(const floatx4*)&sA[r * 32 + p0 * 4];
            floatx4 c1 = *(const floatx4*)&sA[r * 32 + (p0 ^ 1) * 4];
#pragma unroll
            for (int j = 0; j < 4; ++j) {
                aF[i][j]     = (__bf16)c0[j];
                aF[i][4 + j] = (__bf16)c1[j];
            }
        }
#pragma unroll
        for (int i = 0; i < 4; ++i) {
            const int r = nW + i * 16 + l16;
            bf16x4 lo = *(const bf16x4*)&sW[r * LDW + kh * 8];
            bf16x4 hi = *(const bf16x4*)&sW[r * LDW + kh * 8 + 4];
            wF[i] = __builtin_shufflevector(lo, hi, 0, 1, 2, 3, 4, 5, 6, 7);
        }

        // Prefetch W regs for next iter (in flight during MFMA).
        if (kt + BK < K_DIM) {
#pragma unroll
            for (int i = 0; i < 4; ++i)
                pw[i] = *(const floatx4*)(wBase + kt + BK + (size_t)i * 32 * K_DIM);
        }

#pragma unroll
        for (int mi = 0; mi < 4; ++mi)
#pragma unroll
            for (int ni = 0; ni < 4; ++ni)
                acc[mi][ni] = __builtin_amdgcn_mfma_f32_16x16x32_bf16(
                    aF[mi], wF[ni], acc[mi][ni], 0, 0, 0);

        __syncthreads();  // all LDS reads done before next DMA/W-writes

        // Issue A-DMA for next tile (flies until next iter's barrier1).
        if (kt + BK < K_DIM) {
#pragma unroll
            for (int j = 0; j < 4; ++j)
                __builtin_amdgcn_global_load_lds(
                    (const __attribute__((address_space(1))) void*)(aDma[j] + kt + BK),
                    (__attribute__((address_space(3))) void*)&sA[(wave * 32 + j * 8) * 32],
                    16, 0, 0);
        }
    }

    // Epilogue: D mapping col = lane&15, row = (lane>>4)*4 + reg (verified).
#pragma unroll
    for (int ni = 0; ni < 4; ++ni) {
        const int gcol = nBlock + nW + ni * 16 + l16;
        const float bv = bias[gcol];
#pragma unroll
        for (int mi = 0; mi < 4; ++mi) {
            const int rowBase = mBlock + mW + mi * 16 + kh * 4;
#pragma unroll
            for (int r = 0; r < 4; ++r)
                C[(size_t)(rowBase + r) * N_DIM + gcol] = acc[mi][ni][r] + bv;
        }
    }
}

extern "C" void kernel_launch(void* const* d_in, const int* in_sizes, int n_in,
                              void* d_out, int out_size, void* d_ws, size_t ws_size,
                              hipStream_t stream) {
    const float* x = (const float*)d_in[0];
    const float* w = (const float*)d_in[1];
    const float* b = (const float*)d_in[2];
    float* out = (float*)d_out;

    dim3 grid((M_DIM / 128) * (N_DIM / 128));  // 1024 blocks, 1D for swizzle
    dim3 block(256);
    linear_dma<<<grid, block, 0, stream>>>(x, w, b, out);
}